// Round 1
// baseline (2933.635 us; speedup 1.0000x reference)
//
#include <hip/hip_runtime.h>

#define F_IN 256
#define F_OUT 128

// ---------------- GEMM: support = X @ W ----------------
// Tiled fp32 GEMM. BM=64 rows/block, all 128 cols, BK=64 K-tile.
// 256 threads; each thread computes a 4x8 register tile (rows ty*4+i,
// cols {tx*4..tx*4+3, 64+tx*4..64+tx*4+3} to keep LDS reads 2-way max).
__global__ __launch_bounds__(256) void gemm_xw(const float* __restrict__ X,
                                               const float* __restrict__ W,
                                               float* __restrict__ S, int M) {
    const int BM = 64, BK = 64;
    __shared__ float xs[BM][BK];
    __shared__ float ws[BK][F_OUT];
    const int tid = threadIdx.x;
    const int m0 = blockIdx.x * BM;
    const int tx = tid & 15;   // col group
    const int ty = tid >> 4;   // row group

    float acc[4][8];
#pragma unroll
    for (int i = 0; i < 4; i++)
#pragma unroll
        for (int j = 0; j < 8; j++) acc[i][j] = 0.f;

    for (int k0 = 0; k0 < F_IN; k0 += BK) {
        // stage X tile: 64x64 f32 = 1024 float4, 4 iters of 256 lanes
#pragma unroll
        for (int it = 0; it < 4; it++) {
            int idx = it * 256 + tid;
            int r = idx >> 4, c4 = idx & 15;
            int gr = m0 + r;
            float4 v = make_float4(0.f, 0.f, 0.f, 0.f);
            if (gr < M)
                v = reinterpret_cast<const float4*>(X + (size_t)gr * F_IN + k0)[c4];
            reinterpret_cast<float4*>(&xs[r][0])[c4] = v;
        }
        // stage W tile: 64x128 f32 = 2048 float4, 8 iters
#pragma unroll
        for (int it = 0; it < 8; it++) {
            int idx = it * 256 + tid;
            int r = idx >> 5, c4 = idx & 31;
            float4 v = reinterpret_cast<const float4*>(W + (size_t)(k0 + r) * F_OUT)[c4];
            reinterpret_cast<float4*>(&ws[r][0])[c4] = v;
        }
        __syncthreads();
#pragma unroll
        for (int kk = 0; kk < BK; kk++) {
            float a[4], b[8];
#pragma unroll
            for (int i = 0; i < 4; i++) a[i] = xs[ty * 4 + i][kk];
            float4 b0 = reinterpret_cast<const float4*>(&ws[kk][0])[tx];
            float4 b1 = reinterpret_cast<const float4*>(&ws[kk][0])[tx + 16];
            b[0] = b0.x; b[1] = b0.y; b[2] = b0.z; b[3] = b0.w;
            b[4] = b1.x; b[5] = b1.y; b[6] = b1.z; b[7] = b1.w;
#pragma unroll
            for (int i = 0; i < 4; i++)
#pragma unroll
                for (int j = 0; j < 8; j++) acc[i][j] = fmaf(a[i], b[j], acc[i][j]);
        }
        __syncthreads();
    }
#pragma unroll
    for (int i = 0; i < 4; i++) {
        int gr = m0 + ty * 4 + i;
        if (gr >= M) continue;
        float4 v0 = make_float4(acc[i][0], acc[i][1], acc[i][2], acc[i][3]);
        float4 v1 = make_float4(acc[i][4], acc[i][5], acc[i][6], acc[i][7]);
        reinterpret_cast<float4*>(S + (size_t)gr * F_OUT)[tx] = v0;
        reinterpret_cast<float4*>(S + (size_t)gr * F_OUT)[tx + 16] = v1;
    }
}

// ---------------- init: out[n][f] = bias[f] ----------------
__global__ __launch_bounds__(256) void init_out(const float* __restrict__ bias,
                                                float* __restrict__ out, int M) {
    int idx = blockIdx.x * blockDim.x + threadIdx.x;  // float4 index
    int total = M * (F_OUT / 4);
    if (idx >= total) return;
    int c4 = idx & (F_OUT / 4 - 1);
    reinterpret_cast<float4*>(out)[idx] = reinterpret_cast<const float4*>(bias)[c4];
}

// ---------------- scatter: out[row[e]] += val[e] * support[col[e]] ----------------
// 32 lanes per edge; lane l handles float4 l of the 128-wide row
// (gather is one coalesced 512B read per edge; 4 fp32 atomics per lane).
__global__ __launch_bounds__(256) void scatter_edges(const float* __restrict__ support,
                                                     const int* __restrict__ erow,
                                                     const int* __restrict__ ecol,
                                                     const float* __restrict__ eval,
                                                     float* __restrict__ out, int E) {
    long long tid = (long long)blockIdx.x * blockDim.x + threadIdx.x;
    int edge = (int)(tid >> 5);
    int lane = (int)(tid & 31);
    if (edge >= E) return;
    int r = erow[edge];
    int c = ecol[edge];
    float v = eval[edge];
    float4 s = reinterpret_cast<const float4*>(support + (size_t)c * F_OUT)[lane];
    float* o = out + (size_t)r * F_OUT + lane * 4;
    atomicAdd(o + 0, s.x * v);
    atomicAdd(o + 1, s.y * v);
    atomicAdd(o + 2, s.z * v);
    atomicAdd(o + 3, s.w * v);
}

extern "C" void kernel_launch(void* const* d_in, const int* in_sizes, int n_in,
                              void* d_out, int out_size, void* d_ws, size_t ws_size,
                              hipStream_t stream) {
    const float* x    = (const float*)d_in[0];
    const int*   erow = (const int*)d_in[1];
    const int*   ecol = (const int*)d_in[2];
    const float* eval = (const float*)d_in[3];
    const float* w    = (const float*)d_in[4];
    const float* bias = (const float*)d_in[5];
    float* out = (float*)d_out;
    float* support = (float*)d_ws;  // M * F_OUT floats = 51.2 MB, fits ws

    const int M = in_sizes[0] / F_IN;
    const int E = in_sizes[1];

    gemm_xw<<<(M + 63) / 64, 256, 0, stream>>>(x, w, support, M);

    int total4 = M * (F_OUT / 4);
    init_out<<<(total4 + 255) / 256, 256, 0, stream>>>(bias, out, M);

    long long sthreads = (long long)E * 32;
    int sblocks = (int)((sthreads + 255) / 256);
    scatter_edges<<<sblocks, 256, 0, stream>>>(support, erow, ecol, eval, out, E);
}

// Round 2
// 605.940 us; speedup vs baseline: 4.8415x; 4.8415x over previous
//
#include <hip/hip_runtime.h>

#define F_IN 256
#define F_OUT 128

// ---------------- GEMM: support = X @ W ----------------
__global__ __launch_bounds__(256) void gemm_xw(const float* __restrict__ X,
                                               const float* __restrict__ W,
                                               float* __restrict__ S, int M) {
    const int BM = 64, BK = 64;
    __shared__ float xs[BM][BK];
    __shared__ float ws[BK][F_OUT];
    const int tid = threadIdx.x;
    const int m0 = blockIdx.x * BM;
    const int tx = tid & 15;   // col group
    const int ty = tid >> 4;   // row group

    float acc[4][8];
#pragma unroll
    for (int i = 0; i < 4; i++)
#pragma unroll
        for (int j = 0; j < 8; j++) acc[i][j] = 0.f;

    for (int k0 = 0; k0 < F_IN; k0 += BK) {
#pragma unroll
        for (int it = 0; it < 4; it++) {
            int idx = it * 256 + tid;
            int r = idx >> 4, c4 = idx & 15;
            int gr = m0 + r;
            float4 v = make_float4(0.f, 0.f, 0.f, 0.f);
            if (gr < M)
                v = reinterpret_cast<const float4*>(X + (size_t)gr * F_IN + k0)[c4];
            reinterpret_cast<float4*>(&xs[r][0])[c4] = v;
        }
#pragma unroll
        for (int it = 0; it < 8; it++) {
            int idx = it * 256 + tid;
            int r = idx >> 5, c4 = idx & 31;
            float4 v = reinterpret_cast<const float4*>(W + (size_t)(k0 + r) * F_OUT)[c4];
            reinterpret_cast<float4*>(&ws[r][0])[c4] = v;
        }
        __syncthreads();
#pragma unroll
        for (int kk = 0; kk < BK; kk++) {
            float a[4], b[8];
#pragma unroll
            for (int i = 0; i < 4; i++) a[i] = xs[ty * 4 + i][kk];
            float4 b0 = reinterpret_cast<const float4*>(&ws[kk][0])[tx];
            float4 b1 = reinterpret_cast<const float4*>(&ws[kk][0])[tx + 16];
            b[0] = b0.x; b[1] = b0.y; b[2] = b0.z; b[3] = b0.w;
            b[4] = b1.x; b[5] = b1.y; b[6] = b1.z; b[7] = b1.w;
#pragma unroll
            for (int i = 0; i < 4; i++)
#pragma unroll
                for (int j = 0; j < 8; j++) acc[i][j] = fmaf(a[i], b[j], acc[i][j]);
        }
        __syncthreads();
    }
#pragma unroll
    for (int i = 0; i < 4; i++) {
        int gr = m0 + ty * 4 + i;
        if (gr >= M) continue;
        float4 v0 = make_float4(acc[i][0], acc[i][1], acc[i][2], acc[i][3]);
        float4 v1 = make_float4(acc[i][4], acc[i][5], acc[i][6], acc[i][7]);
        reinterpret_cast<float4*>(S + (size_t)gr * F_OUT)[tx] = v0;
        reinterpret_cast<float4*>(S + (size_t)gr * F_OUT)[tx + 16] = v1;
    }
}

// ---------------- CSR build ----------------
// 1) histogram rows into cnt (int atomics, low contention: 100k counters)
__global__ __launch_bounds__(256) void hist_rows(const int* __restrict__ erow,
                                                 int* __restrict__ cnt, int E) {
    for (int e = blockIdx.x * blockDim.x + threadIdx.x; e < E;
         e += gridDim.x * blockDim.x)
        atomicAdd(&cnt[erow[e]], 1);
}

// 2a) per-1024-block exclusive scan; block totals to bsum
__global__ __launch_bounds__(1024) void scan_partial(const int* __restrict__ cnt,
                                                     int* __restrict__ rp,
                                                     int* __restrict__ bsum, int N) {
    __shared__ int sm[1024];
    int t = threadIdx.x;
    int i = blockIdx.x * 1024 + t;
    int v = (i < N) ? cnt[i] : 0;
    sm[t] = v;
    __syncthreads();
#pragma unroll
    for (int off = 1; off < 1024; off <<= 1) {
        int add = (t >= off) ? sm[t - off] : 0;
        __syncthreads();
        sm[t] += add;
        __syncthreads();
    }
    if (i < N) rp[i] = sm[t] - v;            // local exclusive
    if (t == 1023) bsum[blockIdx.x] = sm[t]; // block total
}

// 2b) tiny serial exclusive scan of block sums (~98 entries)
__global__ void scan_bsum(int* bsum, int nb) {
    if (threadIdx.x == 0 && blockIdx.x == 0) {
        int acc = 0;
        for (int i = 0; i < nb; i++) { int v = bsum[i]; bsum[i] = acc; acc += v; }
    }
}

// 2c) add block offsets; produce row_ptr and cursor copy
__global__ __launch_bounds__(256) void scan_add(int* __restrict__ rp,
                                                int* __restrict__ cursor,
                                                const int* __restrict__ bsum,
                                                int N, int E) {
    int i = blockIdx.x * 256 + threadIdx.x;
    if (i < N) {
        int v = rp[i] + bsum[i >> 10];
        rp[i] = v;
        cursor[i] = v;
    }
    if (i == 0) rp[N] = E;
}

// 3) bucket edges into CSR arrays
__global__ __launch_bounds__(256) void bucket_edges(const int* __restrict__ erow,
                                                    const int* __restrict__ ecol,
                                                    const float* __restrict__ eval,
                                                    int* __restrict__ cursor,
                                                    int* __restrict__ ccol,
                                                    float* __restrict__ cval, int E) {
    int e = blockIdx.x * 256 + threadIdx.x;
    if (e >= E) return;
    int r = erow[e];
    int pos = atomicAdd(&cursor[r], 1);
    ccol[pos] = ecol[e];
    cval[pos] = eval[e];
}

// ---------------- gather: out[n] = bias + sum_{e in row n} val*support[col] ----------------
// One wave (64 lanes) per node; lane l owns float2 at offset 2l of the 128-wide row.
__global__ __launch_bounds__(256) void gather_rows(const float* __restrict__ support,
                                                   const int* __restrict__ rp,
                                                   const int* __restrict__ ccol,
                                                   const float* __restrict__ cval,
                                                   const float* __restrict__ bias,
                                                   float* __restrict__ out, int N) {
    int wid = (blockIdx.x * 256 + threadIdx.x) >> 6;  // node
    int lane = threadIdx.x & 63;
    if (wid >= N) return;
    int s = rp[wid], e = rp[wid + 1];
    float2 acc = reinterpret_cast<const float2*>(bias)[lane];
    for (int i = s; i < e; i++) {
        int c = ccol[i];       // uniform across wave -> broadcast
        float v = cval[i];
        float2 sv = reinterpret_cast<const float2*>(support + (size_t)c * F_OUT)[lane];
        acc.x = fmaf(v, sv.x, acc.x);
        acc.y = fmaf(v, sv.y, acc.y);
    }
    reinterpret_cast<float2*>(out + (size_t)wid * F_OUT)[lane] = acc;
}

extern "C" void kernel_launch(void* const* d_in, const int* in_sizes, int n_in,
                              void* d_out, int out_size, void* d_ws, size_t ws_size,
                              hipStream_t stream) {
    const float* x    = (const float*)d_in[0];
    const int*   erow = (const int*)d_in[1];
    const int*   ecol = (const int*)d_in[2];
    const float* eval = (const float*)d_in[3];
    const float* w    = (const float*)d_in[4];
    const float* bias = (const float*)d_in[5];
    float* out = (float*)d_out;

    const int M = in_sizes[0] / F_IN;   // 100000
    const int E = in_sizes[1];          // 1600000

    // workspace layout (bytes)
    char* ws = (char*)d_ws;
    float* support = (float*)(ws);                       // M*F_OUT*4  = 51.2 MB
    int*   ccol    = (int*)  (ws + 51200000);            // E*4        = 6.4 MB
    float* cval    = (float*)(ws + 57600000);            // E*4        = 6.4 MB
    int*   rp      = (int*)  (ws + 64000000);            // (M+1)*4, padded
    int*   cursor  = (int*)  (ws + 64400064);            // M*4
    int*   bsum    = (int*)  (ws + 64800064);            // scan block sums

    // GEMM (independent of CSR build; same stream serializes anyway)
    gemm_xw<<<(M + 63) / 64, 256, 0, stream>>>(x, w, support, M);

    // CSR build
    hipMemsetAsync(cursor, 0, (size_t)M * 4, stream);    // cursor doubles as cnt
    hist_rows<<<2048, 256, 0, stream>>>(erow, cursor, E);
    int nb = (M + 1023) / 1024;
    scan_partial<<<nb, 1024, 0, stream>>>(cursor, rp, bsum, M);
    scan_bsum<<<1, 64, 0, stream>>>(bsum, nb);
    scan_add<<<(M + 255) / 256, 256, 0, stream>>>(rp, cursor, bsum, M, E);
    bucket_edges<<<(E + 255) / 256, 256, 0, stream>>>(erow, ecol, eval, cursor, ccol, cval, E);

    // gather + bias
    int waves = M;  // one wave per node
    gather_rows<<<(waves * 64 + 255) / 256, 256, 0, stream>>>(support, rp, ccol, cval, bias, out, M);
}

// Round 8
// 495.874 us; speedup vs baseline: 5.9161x; 1.2220x over previous
//
#include <hip/hip_runtime.h>

#define F_IN 256
#define F_OUT 128

typedef __bf16 bf16x8 __attribute__((ext_vector_type(8)));
typedef float f32x4 __attribute__((ext_vector_type(4)));

union bfbits { __bf16 b; short s; };

// ---------------- W -> bf16 hi/lo, transposed [128][256] ----------------
__global__ __launch_bounds__(256) void conv_w(const float* __restrict__ W,
                                              short* __restrict__ WTh,
                                              short* __restrict__ WTl) {
    int idx = blockIdx.x * 256 + threadIdx.x;  // over 256*128
    if (idx >= F_IN * F_OUT) return;
    int k = idx >> 7, c = idx & 127;
    float f = W[idx];
    __bf16 h = (__bf16)f;
    float r = f - (float)h;     // exact
    __bf16 l = (__bf16)r;
    bfbits uh, ul; uh.b = h; ul.b = l;
    WTh[c * F_IN + k] = uh.s;
    WTl[c * F_IN + k] = ul.s;
}

// ---------------- GEMM: support = X @ W via split-bf16 MFMA ----------------
// Block = 256 threads = 4 waves; wave handles 64 rows x 128 cols.
// A frags (16x32) straight from global: lane l -> row base+m*16+(l&15),
// k = k0 + 8*(l>>4) + i  (8 contiguous floats = 2 float4 loads, converted
// in-register to bf16 hi/lo). B frags from WTh/WTl[col][k] (L2-resident).
// D layout (m89-verified): col = lane&15, row = (lane>>4)*4 + reg.
// NOTE: even if the assumed within-lane slot->k map differs from HW, A and B
// use the SAME map, and dot-products are invariant under a common K-perm.
__global__ __launch_bounds__(256, 2) void gemm_mfma(const float* __restrict__ X,
                                                    const short* __restrict__ WTh,
                                                    const short* __restrict__ WTl,
                                                    float* __restrict__ S, int M) {
    const int lane = threadIdx.x & 63;
    const int wave = threadIdx.x >> 6;
    const int lr = lane & 15;   // row-in-mtile (A) / col-in-ntile (B,D)
    const int kg = lane >> 4;   // k-group: k-offset 8*kg
    const long long rowbase = (long long)blockIdx.x * 256 + wave * 64;

    f32x4 acc[4][8];
#pragma unroll
    for (int m = 0; m < 4; m++)
#pragma unroll
        for (int n = 0; n < 8; n++) acc[m][n] = (f32x4){0.f, 0.f, 0.f, 0.f};

#pragma unroll
    for (int ks = 0; ks < 8; ks++) {
        const int k0 = ks * 32 + 8 * kg;
        bf16x8 ahi[4], alo[4];
#pragma unroll
        for (int m = 0; m < 4; m++) {
            long long r = rowbase + m * 16 + lr;
            if (r >= M) r = M - 1;           // clamp; stores guarded below
            const float* p = X + r * F_IN + k0;
            float4 f0 = *reinterpret_cast<const float4*>(p);
            float4 f1 = *reinterpret_cast<const float4*>(p + 4);
            float fv[8] = {f0.x, f0.y, f0.z, f0.w, f1.x, f1.y, f1.z, f1.w};
#pragma unroll
            for (int i = 0; i < 8; i++) {
                __bf16 h = (__bf16)fv[i];
                float res = fv[i] - (float)h;
                ahi[m][i] = h;
                alo[m][i] = (__bf16)res;
            }
        }
#pragma unroll
        for (int n = 0; n < 8; n++) {
            const int boff = (n * 16 + lr) * F_IN + k0;
            bf16x8 bhi = *reinterpret_cast<const bf16x8*>(WTh + boff);
            bf16x8 blo = *reinterpret_cast<const bf16x8*>(WTl + boff);
#pragma unroll
            for (int m = 0; m < 4; m++) {
                acc[m][n] = __builtin_amdgcn_mfma_f32_16x16x32_bf16(ahi[m], bhi, acc[m][n], 0, 0, 0);
                acc[m][n] = __builtin_amdgcn_mfma_f32_16x16x32_bf16(ahi[m], blo, acc[m][n], 0, 0, 0);
                acc[m][n] = __builtin_amdgcn_mfma_f32_16x16x32_bf16(alo[m], bhi, acc[m][n], 0, 0, 0);
            }
        }
    }
    // write-out: row = rowbase + m*16 + kg*4 + j, col = n*16 + lr
#pragma unroll
    for (int m = 0; m < 4; m++) {
#pragma unroll
        for (int j = 0; j < 4; j++) {
            long long r = rowbase + m * 16 + kg * 4 + j;
            if (r >= M) continue;
            float* orow = S + r * F_OUT + lr;
#pragma unroll
            for (int n = 0; n < 8; n++) orow[n * 16] = acc[m][n][j];
        }
    }
}

// ---------------- CSR build ----------------
__global__ __launch_bounds__(256) void hist_rows(const int* __restrict__ erow,
                                                 int* __restrict__ cnt, int E) {
    for (int e = blockIdx.x * blockDim.x + threadIdx.x; e < E;
         e += gridDim.x * blockDim.x)
        atomicAdd(&cnt[erow[e]], 1);
}

__global__ __launch_bounds__(1024) void scan_partial(const int* __restrict__ cnt,
                                                     int* __restrict__ rp,
                                                     int* __restrict__ bsum, int N) {
    __shared__ int sm[1024];
    int t = threadIdx.x;
    int i = blockIdx.x * 1024 + t;
    int v = (i < N) ? cnt[i] : 0;
    sm[t] = v;
    __syncthreads();
#pragma unroll
    for (int off = 1; off < 1024; off <<= 1) {
        int add = (t >= off) ? sm[t - off] : 0;
        __syncthreads();
        sm[t] += add;
        __syncthreads();
    }
    if (i < N) rp[i] = sm[t] - v;
    if (t == 1023) bsum[blockIdx.x] = sm[t];
}

// parallel exclusive scan of block sums (nb <= 128)
__global__ void scan_bsum(int* bsum, int nb) {
    __shared__ int sm[128];
    int t = threadIdx.x;
    int v = (t < nb) ? bsum[t] : 0;
    sm[t] = v;
    __syncthreads();
#pragma unroll
    for (int off = 1; off < 128; off <<= 1) {
        int add = (t >= off) ? sm[t - off] : 0;
        __syncthreads();
        sm[t] += add;
        __syncthreads();
    }
    if (t < nb) bsum[t] = sm[t] - v;
}

__global__ __launch_bounds__(256) void scan_add(int* __restrict__ rp,
                                                int* __restrict__ cursor,
                                                const int* __restrict__ bsum,
                                                int N, int E) {
    int i = blockIdx.x * 256 + threadIdx.x;
    if (i < N) {
        int v = rp[i] + bsum[i >> 10];
        rp[i] = v;
        cursor[i] = v;
    }
    if (i == 0) rp[N] = E;
}

__global__ __launch_bounds__(256) void bucket_edges(const int* __restrict__ erow,
                                                    const int* __restrict__ ecol,
                                                    const float* __restrict__ eval,
                                                    int* __restrict__ cursor,
                                                    int* __restrict__ ccol,
                                                    float* __restrict__ cval, int E) {
    int e = blockIdx.x * 256 + threadIdx.x;
    if (e >= E) return;
    int r = erow[e];
    int pos = atomicAdd(&cursor[r], 1);
    ccol[pos] = ecol[e];
    cval[pos] = eval[e];
}

// ---------------- gather: out[n] = bias + sum val*support[col], unroll x4 ----------------
__global__ __launch_bounds__(256) void gather_rows(const float* __restrict__ support,
                                                   const int* __restrict__ rp,
                                                   const int* __restrict__ ccol,
                                                   const float* __restrict__ cval,
                                                   const float* __restrict__ bias,
                                                   float* __restrict__ out, int N) {
    int wid = (blockIdx.x * 256 + threadIdx.x) >> 6;
    int lane = threadIdx.x & 63;
    if (wid >= N) return;
    int s = rp[wid], e = rp[wid + 1];
    const float2* S2 = reinterpret_cast<const float2*>(support);
    float2 acc = reinterpret_cast<const float2*>(bias)[lane];
    int i = s;
    for (; i + 4 <= e; i += 4) {
        int c0 = ccol[i], c1 = ccol[i + 1], c2 = ccol[i + 2], c3 = ccol[i + 3];
        float v0 = cval[i], v1 = cval[i + 1], v2 = cval[i + 2], v3 = cval[i + 3];
        float2 s0 = S2[(size_t)c0 * 64 + lane];
        float2 s1 = S2[(size_t)c1 * 64 + lane];
        float2 s2 = S2[(size_t)c2 * 64 + lane];
        float2 s3 = S2[(size_t)c3 * 64 + lane];
        acc.x = fmaf(v0, s0.x, acc.x); acc.y = fmaf(v0, s0.y, acc.y);
        acc.x = fmaf(v1, s1.x, acc.x); acc.y = fmaf(v1, s1.y, acc.y);
        acc.x = fmaf(v2, s2.x, acc.x); acc.y = fmaf(v2, s2.y, acc.y);
        acc.x = fmaf(v3, s3.x, acc.x); acc.y = fmaf(v3, s3.y, acc.y);
    }
    for (; i < e; i++) {
        int c = ccol[i];
        float v = cval[i];
        float2 sv = S2[(size_t)c * 64 + lane];
        acc.x = fmaf(v, sv.x, acc.x);
        acc.y = fmaf(v, sv.y, acc.y);
    }
    reinterpret_cast<float2*>(out)[(size_t)wid * 64 + lane] = acc;
}

extern "C" void kernel_launch(void* const* d_in, const int* in_sizes, int n_in,
                              void* d_out, int out_size, void* d_ws, size_t ws_size,
                              hipStream_t stream) {
    const float* x    = (const float*)d_in[0];
    const int*   erow = (const int*)d_in[1];
    const int*   ecol = (const int*)d_in[2];
    const float* eval = (const float*)d_in[3];
    const float* w    = (const float*)d_in[4];
    const float* bias = (const float*)d_in[5];
    float* out = (float*)d_out;

    const int M = in_sizes[0] / F_IN;   // 100000
    const int E = in_sizes[1];          // 1600000

    // Workspace layout. Peak footprint identical to the R2-passing kernel
    // (64.80 MB): WTh/WTl OVERLAY the ccol region — they are dead by the
    // time bucket_edges writes ccol/cval (same-stream serialization).
    char* ws = (char*)d_ws;
    float* support = (float*)(ws);                 // 51.2 MB
    int*   ccol    = (int*)  (ws + 51200000);      // 6.4 MB  (after GEMM)
    float* cval    = (float*)(ws + 57600000);      // 6.4 MB  (after GEMM)
    int*   rp      = (int*)  (ws + 64000000);      // (M+1)*4
    int*   cursor  = (int*)  (ws + 64400064);      // M*4
    int*   bsum    = (int*)  (ws + 64800064);      // 512 B
    short* WTh     = (short*)(ws + 51200000);      // 64 KB (overlays ccol)
    short* WTl     = (short*)(ws + 51265536);      // 64 KB (overlays ccol)

    // W -> bf16 hi/lo transposed (tiny)
    conv_w<<<(F_IN * F_OUT + 255) / 256, 256, 0, stream>>>(w, WTh, WTl);

    // GEMM (MFMA, split-bf16)
    gemm_mfma<<<(M + 255) / 256, 256, 0, stream>>>(x, WTh, WTl, support, M);

    // CSR build (ccol/cval written only after GEMM is done -> overlay safe)
    hipMemsetAsync(cursor, 0, (size_t)M * 4, stream);
    hist_rows<<<2048, 256, 0, stream>>>(erow, cursor, E);
    int nb = (M + 1023) / 1024;
    scan_partial<<<nb, 1024, 0, stream>>>(cursor, rp, bsum, M);
    scan_bsum<<<1, 128, 0, stream>>>(bsum, nb);
    scan_add<<<(M + 255) / 256, 256, 0, stream>>>(rp, cursor, bsum, M, E);
    bucket_edges<<<(E + 255) / 256, 256, 0, stream>>>(erow, ecol, eval, cursor, ccol, cval, E);

    // gather + bias
    gather_rows<<<((size_t)M * 64 + 255) / 256, 256, 0, stream>>>(support, rp, ccol, cval, bias, out, M);
}

// Round 15
// 466.766 us; speedup vs baseline: 6.2850x; 1.0624x over previous
//
#include <hip/hip_runtime.h>

#define F_IN 256
#define F_OUT 128

typedef __bf16 bf16x8 __attribute__((ext_vector_type(8)));
typedef float f32x4 __attribute__((ext_vector_type(4)));

union bfbits { __bf16 b; short s; };

// ---------------- W -> bf16 hi/lo, transposed [128][256] ----------------
__global__ __launch_bounds__(256) void conv_w(const float* __restrict__ W,
                                              short* __restrict__ WTh,
                                              short* __restrict__ WTl) {
    int idx = blockIdx.x * 256 + threadIdx.x;  // over 256*128
    if (idx >= F_IN * F_OUT) return;
    int k = idx >> 7, c = idx & 127;
    float f = W[idx];
    __bf16 h = (__bf16)f;
    float r = f - (float)h;     // exact
    __bf16 l = (__bf16)r;
    bfbits uh, ul; uh.b = h; ul.b = l;
    WTh[c * F_IN + k] = uh.s;
    WTl[c * F_IN + k] = ul.s;
}

// ---------------- GEMM: support = X @ W via split-bf16 MFMA ----------------
// (unchanged from R8-passing version; left the top-5 at <114 us)
__global__ __launch_bounds__(256, 2) void gemm_mfma(const float* __restrict__ X,
                                                    const short* __restrict__ WTh,
                                                    const short* __restrict__ WTl,
                                                    float* __restrict__ S, int M) {
    const int lane = threadIdx.x & 63;
    const int wave = threadIdx.x >> 6;
    const int lr = lane & 15;   // row-in-mtile (A) / col-in-ntile (B,D)
    const int kg = lane >> 4;   // k-group: k-offset 8*kg
    const long long rowbase = (long long)blockIdx.x * 256 + wave * 64;

    f32x4 acc[4][8];
#pragma unroll
    for (int m = 0; m < 4; m++)
#pragma unroll
        for (int n = 0; n < 8; n++) acc[m][n] = (f32x4){0.f, 0.f, 0.f, 0.f};

#pragma unroll
    for (int ks = 0; ks < 8; ks++) {
        const int k0 = ks * 32 + 8 * kg;
        bf16x8 ahi[4], alo[4];
#pragma unroll
        for (int m = 0; m < 4; m++) {
            long long r = rowbase + m * 16 + lr;
            if (r >= M) r = M - 1;           // clamp; stores guarded below
            const float* p = X + r * F_IN + k0;
            float4 f0 = *reinterpret_cast<const float4*>(p);
            float4 f1 = *reinterpret_cast<const float4*>(p + 4);
            float fv[8] = {f0.x, f0.y, f0.z, f0.w, f1.x, f1.y, f1.z, f1.w};
#pragma unroll
            for (int i = 0; i < 8; i++) {
                __bf16 h = (__bf16)fv[i];
                float res = fv[i] - (float)h;
                ahi[m][i] = h;
                alo[m][i] = (__bf16)res;
            }
        }
#pragma unroll
        for (int n = 0; n < 8; n++) {
            const int boff = (n * 16 + lr) * F_IN + k0;
            bf16x8 bhi = *reinterpret_cast<const bf16x8*>(WTh + boff);
            bf16x8 blo = *reinterpret_cast<const bf16x8*>(WTl + boff);
#pragma unroll
            for (int m = 0; m < 4; m++) {
                acc[m][n] = __builtin_amdgcn_mfma_f32_16x16x32_bf16(ahi[m], bhi, acc[m][n], 0, 0, 0);
                acc[m][n] = __builtin_amdgcn_mfma_f32_16x16x32_bf16(ahi[m], blo, acc[m][n], 0, 0, 0);
                acc[m][n] = __builtin_amdgcn_mfma_f32_16x16x32_bf16(alo[m], bhi, acc[m][n], 0, 0, 0);
            }
        }
    }
    // write-out: row = rowbase + m*16 + kg*4 + j, col = n*16 + lr
#pragma unroll
    for (int m = 0; m < 4; m++) {
#pragma unroll
        for (int j = 0; j < 4; j++) {
            long long r = rowbase + m * 16 + kg * 4 + j;
            if (r >= M) continue;
            float* orow = S + r * F_OUT + lr;
#pragma unroll
            for (int n = 0; n < 8; n++) orow[n * 16] = acc[m][n][j];
        }
    }
}

// ---------------- CSR build (rank-fused, atomic-free scatter) ----------------
// hist + rank: the hist atomic's return value IS the edge's rank in its row.
__global__ __launch_bounds__(256) void hist_rank(const int* __restrict__ erow,
                                                 int* __restrict__ cnt,
                                                 int* __restrict__ rank, int E) {
    for (int e = blockIdx.x * blockDim.x + threadIdx.x; e < E;
         e += gridDim.x * blockDim.x)
        rank[e] = atomicAdd(&cnt[erow[e]], 1);
}

__global__ __launch_bounds__(1024) void scan_partial(const int* __restrict__ cnt,
                                                     int* __restrict__ rp,
                                                     int* __restrict__ bsum, int N) {
    __shared__ int sm[1024];
    int t = threadIdx.x;
    int i = blockIdx.x * 1024 + t;
    int v = (i < N) ? cnt[i] : 0;
    sm[t] = v;
    __syncthreads();
#pragma unroll
    for (int off = 1; off < 1024; off <<= 1) {
        int add = (t >= off) ? sm[t - off] : 0;
        __syncthreads();
        sm[t] += add;
        __syncthreads();
    }
    if (i < N) rp[i] = sm[t] - v;
    if (t == 1023) bsum[blockIdx.x] = sm[t];
}

// parallel exclusive scan of block sums (nb <= 128)
__global__ void scan_bsum(int* bsum, int nb) {
    __shared__ int sm[128];
    int t = threadIdx.x;
    int v = (t < nb) ? bsum[t] : 0;
    sm[t] = v;
    __syncthreads();
#pragma unroll
    for (int off = 1; off < 128; off <<= 1) {
        int add = (t >= off) ? sm[t - off] : 0;
        __syncthreads();
        sm[t] += add;
        __syncthreads();
    }
    if (t < nb) bsum[t] = sm[t] - v;
}

__global__ __launch_bounds__(256) void scan_add(int* __restrict__ rp,
                                                const int* __restrict__ bsum,
                                                int N, int E) {
    int i = blockIdx.x * 256 + threadIdx.x;
    if (i < N) rp[i] += bsum[i >> 10];
    if (i == 0) rp[N] = E;
}

// atomic-free scatter: position is rp[row] + rank. 4B per edge (edge id only).
__global__ __launch_bounds__(256) void bucket_perm(const int* __restrict__ erow,
                                                   const int* __restrict__ rank,
                                                   const int* __restrict__ rp,
                                                   int* __restrict__ perm, int E) {
    int e = blockIdx.x * 256 + threadIdx.x;
    if (e >= E) return;
    perm[rp[erow[e]] + rank[e]] = e;
}

// ---------------- gather: out[n] = bias + sum val*support[col], unroll x8 ----------------
// One wave per node; lane owns float2 of the 128-wide row. Edge ids via perm;
// ecol/eval are 6.4MB each -> L2/L3-resident broadcast loads. Unroll 8 gives
// 8 independent 512B row-gathers in flight per wave (latency-bound phase).
__global__ __launch_bounds__(256) void gather_rows(const float* __restrict__ support,
                                                   const int* __restrict__ rp,
                                                   const int* __restrict__ perm,
                                                   const int* __restrict__ ecol,
                                                   const float* __restrict__ eval,
                                                   const float* __restrict__ bias,
                                                   float* __restrict__ out, int N) {
    int wid = (blockIdx.x * 256 + threadIdx.x) >> 6;
    int lane = threadIdx.x & 63;
    if (wid >= N) return;
    int s = rp[wid], e = rp[wid + 1];
    const float2* S2 = reinterpret_cast<const float2*>(support);
    float2 acc = reinterpret_cast<const float2*>(bias)[lane];
    int i = s;
    for (; i + 8 <= e; i += 8) {
        int ee[8]; int cc[8]; float vv[8]; float2 ss[8];
#pragma unroll
        for (int j = 0; j < 8; j++) ee[j] = perm[i + j];
#pragma unroll
        for (int j = 0; j < 8; j++) { cc[j] = ecol[ee[j]]; vv[j] = eval[ee[j]]; }
#pragma unroll
        for (int j = 0; j < 8; j++) ss[j] = S2[(size_t)cc[j] * 64 + lane];
#pragma unroll
        for (int j = 0; j < 8; j++) {
            acc.x = fmaf(vv[j], ss[j].x, acc.x);
            acc.y = fmaf(vv[j], ss[j].y, acc.y);
        }
    }
    for (; i + 4 <= e; i += 4) {
        int ee[4]; int cc[4]; float vv[4]; float2 ss[4];
#pragma unroll
        for (int j = 0; j < 4; j++) ee[j] = perm[i + j];
#pragma unroll
        for (int j = 0; j < 4; j++) { cc[j] = ecol[ee[j]]; vv[j] = eval[ee[j]]; }
#pragma unroll
        for (int j = 0; j < 4; j++) ss[j] = S2[(size_t)cc[j] * 64 + lane];
#pragma unroll
        for (int j = 0; j < 4; j++) {
            acc.x = fmaf(vv[j], ss[j].x, acc.x);
            acc.y = fmaf(vv[j], ss[j].y, acc.y);
        }
    }
    for (; i < e; i++) {
        int e0 = perm[i];
        int c = ecol[e0];
        float v = eval[e0];
        float2 sv = S2[(size_t)c * 64 + lane];
        acc.x = fmaf(v, sv.x, acc.x);
        acc.y = fmaf(v, sv.y, acc.y);
    }
    reinterpret_cast<float2*>(out)[(size_t)wid * 64 + lane] = acc;
}

extern "C" void kernel_launch(void* const* d_in, const int* in_sizes, int n_in,
                              void* d_out, int out_size, void* d_ws, size_t ws_size,
                              hipStream_t stream) {
    const float* x    = (const float*)d_in[0];
    const int*   erow = (const int*)d_in[1];
    const int*   ecol = (const int*)d_in[2];
    const float* eval = (const float*)d_in[3];
    const float* w    = (const float*)d_in[4];
    const float* bias = (const float*)d_in[5];
    float* out = (float*)d_out;

    const int M = in_sizes[0] / F_IN;   // 100000
    const int E = in_sizes[1];          // 1600000

    // Workspace layout — peak footprint IDENTICAL to the R2/R8-proven
    // 64,800,576 bytes. WTh/WTl overlay perm (dead before bucket_perm).
    char* ws = (char*)d_ws;
    float* support = (float*)(ws);                 // 51.2 MB
    int*   perm    = (int*)  (ws + 51200000);      // 6.4 MB (written in bucket)
    int*   rank    = (int*)  (ws + 57600000);      // 6.4 MB (hist -> bucket)
    int*   rp      = (int*)  (ws + 64000000);      // (M+1)*4
    int*   cnt     = (int*)  (ws + 64400064);      // M*4
    int*   bsum    = (int*)  (ws + 64800064);      // 512 B
    short* WTh     = (short*)(ws + 51200000);      // 64 KB (overlays perm)
    short* WTl     = (short*)(ws + 51265536);      // 64 KB (overlays perm)

    // W -> bf16 hi/lo transposed (tiny)
    conv_w<<<(F_IN * F_OUT + 255) / 256, 256, 0, stream>>>(w, WTh, WTl);

    // GEMM (MFMA, split-bf16)
    gemm_mfma<<<(M + 255) / 256, 256, 0, stream>>>(x, WTh, WTl, support, M);

    // CSR build: hist(+rank) -> scan -> atomic-free scatter of edge ids
    hipMemsetAsync(cnt, 0, (size_t)M * 4, stream);
    hist_rank<<<2048, 256, 0, stream>>>(erow, cnt, rank, E);
    int nb = (M + 1023) / 1024;
    scan_partial<<<nb, 1024, 0, stream>>>(cnt, rp, bsum, M);
    scan_bsum<<<1, 128, 0, stream>>>(bsum, nb);
    scan_add<<<(M + 255) / 256, 256, 0, stream>>>(rp, bsum, M, E);
    bucket_perm<<<(E + 255) / 256, 256, 0, stream>>>(erow, rank, rp, perm, E);

    // gather + bias
    gather_rows<<<((size_t)M * 64 + 255) / 256, 256, 0, stream>>>(support, rp, perm, ecol, eval, bias, out, M);
}